// Round 5
// baseline (1298.255 us; speedup 1.0000x reference)
//
#include <hip/hip_runtime.h>
#include <math.h>

#define T_STEPS 8
#define N_NODES 20000
#define F_IN    128
#define H_DIM   256
#define E_EDGES 320000

#define G_UPD    625     // update tiles (20000/32)
#define G_AGG    5000    // 625 node-groups x 8 col-chunks

typedef __attribute__((ext_vector_type(8))) short short8;
typedef __attribute__((ext_vector_type(4))) float f32x4;

__device__ __forceinline__ void split2(float v, unsigned short& h, unsigned short& l) {
    unsigned vi = __float_as_uint(v);
    h = (unsigned short)(vi >> 16);
    float hf = __uint_as_float(vi & 0xffff0000u);
    l = (unsigned short)(__float_as_uint(v - hf) >> 16);
}

// ---------------- CSR build ----------------

__global__ void count_kernel(const int* __restrict__ dst, int* __restrict__ counts, int E) {
    int e = blockIdx.x * blockDim.x + threadIdx.x;
    if (e < E) atomicAdd(&counts[dst[e]], 1);
}

__global__ void scan_kernel(const int* __restrict__ counts, int* __restrict__ row_ptr,
                            int* __restrict__ cursors, int n) {
    __shared__ int buf[1024];
    __shared__ int carry_s;
    int tid = threadIdx.x;
    if (tid == 0) carry_s = 0;
    __syncthreads();
    for (int base = 0; base < n; base += 1024) {
        int i = base + tid;
        int v = (i < n) ? counts[i] : 0;
        buf[tid] = v;
        __syncthreads();
        for (int off = 1; off < 1024; off <<= 1) {
            int t = (tid >= off) ? buf[tid - off] : 0;
            __syncthreads();
            buf[tid] += t;
            __syncthreads();
        }
        int incl = buf[tid];
        int carry = carry_s;
        if (i < n) {
            int ex = carry + incl - v;
            row_ptr[i] = ex;
            cursors[i] = ex;
        }
        __syncthreads();
        if (tid == 1023) carry_s = carry + incl;
        __syncthreads();
    }
    if (tid == 0) row_ptr[n] = carry_s;
}

// col stored as ushort (N_NODES < 65536): halves index traffic, helps L2 residency
__global__ void fill_kernel(const int* __restrict__ src, const int* __restrict__ dst,
                            int* __restrict__ cursors, unsigned short* __restrict__ col, int E) {
    int e = blockIdx.x * blockDim.x + threadIdx.x;
    if (e < E) {
        int d = dst[e];
        int p = atomicAdd(&cursors[d], 1);
        col[p] = (unsigned short)src[e];
    }
}

// ---------------- weight fp32 -> MFMA-fragment-major bf16 hi/lo ----------------

__global__ void cvt_frag(const float* __restrict__ W, int K,
                         unsigned short* __restrict__ fh, unsigned short* __restrict__ fl) {
    int g = blockIdx.x * 256 + threadIdx.x;
    int KP32 = K >> 5;
    int total = (H_DIM / 16) * KP32 * 64;
    if (g >= total) return;
    int lane = g & 63;
    int kp = (g >> 6) % KP32;
    int rt = g / (KP32 << 6);
    int r = rt * 16 + (lane & 15);
    int c = kp * 32 + (lane >> 4) * 8;
    const float* p = W + (size_t)r * K + c;
    short8 h, l;
    #pragma unroll
    for (int j = 0; j < 8; ++j) {
        unsigned short hh, ll;
        split2(p[j], hh, ll);
        h[j] = (short)hh; l[j] = (short)ll;
    }
    *(short8*)(fh + (size_t)g * 8) = h;
    *(short8*)(fl + (size_t)g * 8) = l;
}

// ---------------- gather kernel (standalone dispatch, optionally dual-buffer) --
// chunk = blockIdx&7 -> XCD pin (r2: FETCH 300->44 MB); runs alone so the
// 2.56 MB per-XCD state slice stays L2-resident (r3: co-resident streaming
// evicts it). r4 measured ~40 us vs ~12 us floor with only 2 loads in flight
// per lane and rows strictly serial -> this version runs ALL 8 of the wave's
// rows as concurrent chains: 8 col loads + 8 src loads outstanding per lane.
// Dual-buffer mode (grid = 2*G_AGG): blocks [0,G_AGG) gather bufA,
// [G_AGG,2*G_AGG) gather bufB. G_AGG % 8 == 0 keeps the chunk->XCD pin; per
// XCD, dispatch order finishes sliceA before sliceB (one slice in L2 at a time).

__global__ __launch_bounds__(256) void agg_kernel(
        const float* __restrict__ gsrcA, float* __restrict__ goutA,
        const float* __restrict__ gsrcB, float* __restrict__ goutB,
        const int* __restrict__ row_ptr, const unsigned short* __restrict__ col) {
    int b = blockIdx.x;
    const float* gsrc = gsrcA;
    float* gout = goutA;
    if (b >= G_AGG) { b -= G_AGG; gsrc = gsrcB; gout = goutB; }
    const int tid = threadIdx.x;
    const int lane = tid & 63, w = tid >> 6;
    const int chunk = b & 7;       // XCD pin
    const int nb = b >> 3;
    const int slot = lane >> 3, comp = lane & 7;
    const float4* src4 = (const float4*)gsrc + (size_t)chunk * 8 + comp;
    const int r0 = nb * 32 + w * 8;

    int jj[8], en[8];
    float4 ac[8];
    #pragma unroll
    for (int k = 0; k < 8; ++k) {
        jj[k] = row_ptr[r0 + k] + slot;
        en[k] = row_ptr[r0 + k + 1];
        ac[k] = (float4){0.f, 0.f, 0.f, 0.f};
    }
    while (true) {
        bool ok[8];
        int ix[8];
        bool anyv = false;
        #pragma unroll
        for (int k = 0; k < 8; ++k) {
            ok[k] = jj[k] < en[k];
            anyv |= ok[k];
            ix[k] = ok[k] ? jj[k] : 0;
        }
        if (!anyv) break;
        int cc[8];
        #pragma unroll
        for (int k = 0; k < 8; ++k) cc[k] = col[ix[k]];
        #pragma unroll
        for (int k = 0; k < 8; ++k) {
            float4 v = src4[(size_t)cc[k] * 64];
            if (ok[k]) {
                ac[k].x += v.x; ac[k].y += v.y; ac[k].z += v.z; ac[k].w += v.w;
                jj[k] += 8;
            }
        }
    }
    // cross-slot reduce (slots differ in lane bits 3..5)
    #pragma unroll
    for (int k = 0; k < 8; ++k) {
        #pragma unroll
        for (int m = 8; m < 64; m <<= 1) {
            ac[k].x += __shfl_xor(ac[k].x, m);
            ac[k].y += __shfl_xor(ac[k].y, m);
            ac[k].z += __shfl_xor(ac[k].z, m);
            ac[k].w += __shfl_xor(ac[k].w, m);
        }
    }
    if (slot == 0) {
        #pragma unroll
        for (int k = 0; k < 8; ++k)
            *(float4*)(gout + (size_t)(r0 + k) * 256 + chunk * 32 + comp * 4) = ac[k];
    }
}

// ---------------- update kernel ----------------
// Pure dense MFMA update, 32 rows x 256 cols per block, 4 waves.
// Part 1: A = inp (fp32 global), Part 2: A = AGG (fp32 global).
// r4 post-mortem: VALUBusy*dur matches computed VALU work (~18 us) -> ~80% of
// the 83 us is stall on the per-kp A-load (HBM ~900 cy) serialized by
// unroll 1. Fix: explicit one-kp-ahead A prefetch (pv/nv) so the load of
// kp+1 overlaps split2+MFMA of kp. B frags are L2-hot (weights, 256 KB).

__device__ __forceinline__ void upd_body(
        const float* __restrict__ A1, int K1,
        const float* __restrict__ s_prev,
        const unsigned short* __restrict__ B1h, const unsigned short* __restrict__ B1l,
        const unsigned short* __restrict__ B2h, const unsigned short* __restrict__ B2l,
        const float* __restrict__ AGGu,
        float* __restrict__ s_new,
        const float* __restrict__ leak_ptr, int m0) {
    const int tid = threadIdx.x;
    const int lane = tid & 63, w = tid >> 6;
    const int fr = lane & 15, fq = lane >> 4;
    const int wn = w * 64;
    const int rtbase = w * 4;

    f32x4 acc[2][4];
    #pragma unroll
    for (int mi = 0; mi < 2; ++mi)
        #pragma unroll
        for (int nt = 0; nt < 4; ++nt)
            acc[mi][nt] = (f32x4){0.f, 0.f, 0.f, 0.f};

    // ---- part 1: dense A1, software-pipelined A loads ----
    {
        const int KP32 = K1 >> 5;
        const float* ar0 = A1 + (size_t)(m0 + fr) * K1 + fq * 8;
        const float* ar1 = A1 + (size_t)(m0 + 16 + fr) * K1 + fq * 8;
        float4 pA0, pA1, pB0, pB1;
        pA0 = *(const float4*)ar0;
        pA1 = *(const float4*)(ar0 + 4);
        pB0 = *(const float4*)ar1;
        pB1 = *(const float4*)(ar1 + 4);
        #pragma unroll 1
        for (int kp = 0; kp < KP32; ++kp) {
            const int kpn = (kp + 1 < KP32) ? kp + 1 : kp;
            float4 nA0 = *(const float4*)(ar0 + kpn * 32);
            float4 nA1 = *(const float4*)(ar0 + kpn * 32 + 4);
            float4 nB0 = *(const float4*)(ar1 + kpn * 32);
            float4 nB1 = *(const float4*)(ar1 + kpn * 32 + 4);
            short8 bh[4], bl[4];
            #pragma unroll
            for (int nt = 0; nt < 4; ++nt) {
                size_t off = ((size_t)((rtbase + nt) * KP32 + kp) * 64 + lane) * 8;
                bh[nt] = *(const short8*)(B1h + off);
                bl[nt] = *(const short8*)(B1l + off);
            }
            short8 ah[2], al[2];
            {
                unsigned short h, l;
                split2(pA0.x, h, l); ah[0][0] = (short)h; al[0][0] = (short)l;
                split2(pA0.y, h, l); ah[0][1] = (short)h; al[0][1] = (short)l;
                split2(pA0.z, h, l); ah[0][2] = (short)h; al[0][2] = (short)l;
                split2(pA0.w, h, l); ah[0][3] = (short)h; al[0][3] = (short)l;
                split2(pA1.x, h, l); ah[0][4] = (short)h; al[0][4] = (short)l;
                split2(pA1.y, h, l); ah[0][5] = (short)h; al[0][5] = (short)l;
                split2(pA1.z, h, l); ah[0][6] = (short)h; al[0][6] = (short)l;
                split2(pA1.w, h, l); ah[0][7] = (short)h; al[0][7] = (short)l;
                split2(pB0.x, h, l); ah[1][0] = (short)h; al[1][0] = (short)l;
                split2(pB0.y, h, l); ah[1][1] = (short)h; al[1][1] = (short)l;
                split2(pB0.z, h, l); ah[1][2] = (short)h; al[1][2] = (short)l;
                split2(pB0.w, h, l); ah[1][3] = (short)h; al[1][3] = (short)l;
                split2(pB1.x, h, l); ah[1][4] = (short)h; al[1][4] = (short)l;
                split2(pB1.y, h, l); ah[1][5] = (short)h; al[1][5] = (short)l;
                split2(pB1.z, h, l); ah[1][6] = (short)h; al[1][6] = (short)l;
                split2(pB1.w, h, l); ah[1][7] = (short)h; al[1][7] = (short)l;
            }
            #pragma unroll
            for (int mi = 0; mi < 2; ++mi)
                #pragma unroll
                for (int nt = 0; nt < 4; ++nt) {
                    f32x4 c = acc[mi][nt];
                    c = __builtin_amdgcn_mfma_f32_16x16x32_bf16(ah[mi], bh[nt], c, 0, 0, 0);
                    c = __builtin_amdgcn_mfma_f32_16x16x32_bf16(al[mi], bh[nt], c, 0, 0, 0);
                    c = __builtin_amdgcn_mfma_f32_16x16x32_bf16(ah[mi], bl[nt], c, 0, 0, 0);
                    acc[mi][nt] = c;
                }
            pA0 = nA0; pA1 = nA1; pB0 = nB0; pB1 = nB1;
        }
    }

    // ---- part 2: A = AGG (dense fp32 global, K = 256), same pipelining ----
    if (B2h) {
        const float* ar0 = AGGu + (size_t)(m0 + fr) * H_DIM + fq * 8;
        const float* ar1 = AGGu + (size_t)(m0 + 16 + fr) * H_DIM + fq * 8;
        float4 pA0, pA1, pB0, pB1;
        pA0 = *(const float4*)ar0;
        pA1 = *(const float4*)(ar0 + 4);
        pB0 = *(const float4*)ar1;
        pB1 = *(const float4*)(ar1 + 4);
        #pragma unroll 1
        for (int kp = 0; kp < 8; ++kp) {
            const int kpn = (kp + 1 < 8) ? kp + 1 : kp;
            float4 nA0 = *(const float4*)(ar0 + kpn * 32);
            float4 nA1 = *(const float4*)(ar0 + kpn * 32 + 4);
            float4 nB0 = *(const float4*)(ar1 + kpn * 32);
            float4 nB1 = *(const float4*)(ar1 + kpn * 32 + 4);
            short8 bh[4], bl[4];
            #pragma unroll
            for (int nt = 0; nt < 4; ++nt) {
                size_t off = ((size_t)((rtbase + nt) * 8 + kp) * 64 + lane) * 8;
                bh[nt] = *(const short8*)(B2h + off);
                bl[nt] = *(const short8*)(B2l + off);
            }
            short8 ah[2], al[2];
            {
                unsigned short h, l;
                split2(pA0.x, h, l); ah[0][0] = (short)h; al[0][0] = (short)l;
                split2(pA0.y, h, l); ah[0][1] = (short)h; al[0][1] = (short)l;
                split2(pA0.z, h, l); ah[0][2] = (short)h; al[0][2] = (short)l;
                split2(pA0.w, h, l); ah[0][3] = (short)h; al[0][3] = (short)l;
                split2(pA1.x, h, l); ah[0][4] = (short)h; al[0][4] = (short)l;
                split2(pA1.y, h, l); ah[0][5] = (short)h; al[0][5] = (short)l;
                split2(pA1.z, h, l); ah[0][6] = (short)h; al[0][6] = (short)l;
                split2(pA1.w, h, l); ah[0][7] = (short)h; al[0][7] = (short)l;
                split2(pB0.x, h, l); ah[1][0] = (short)h; al[1][0] = (short)l;
                split2(pB0.y, h, l); ah[1][1] = (short)h; al[1][1] = (short)l;
                split2(pB0.z, h, l); ah[1][2] = (short)h; al[1][2] = (short)l;
                split2(pB0.w, h, l); ah[1][3] = (short)h; al[1][3] = (short)l;
                split2(pB1.x, h, l); ah[1][4] = (short)h; al[1][4] = (short)l;
                split2(pB1.y, h, l); ah[1][5] = (short)h; al[1][5] = (short)l;
                split2(pB1.z, h, l); ah[1][6] = (short)h; al[1][6] = (short)l;
                split2(pB1.w, h, l); ah[1][7] = (short)h; al[1][7] = (short)l;
            }
            #pragma unroll
            for (int mi = 0; mi < 2; ++mi)
                #pragma unroll
                for (int nt = 0; nt < 4; ++nt) {
                    f32x4 c = acc[mi][nt];
                    c = __builtin_amdgcn_mfma_f32_16x16x32_bf16(ah[mi], bh[nt], c, 0, 0, 0);
                    c = __builtin_amdgcn_mfma_f32_16x16x32_bf16(al[mi], bh[nt], c, 0, 0, 0);
                    c = __builtin_amdgcn_mfma_f32_16x16x32_bf16(ah[mi], bl[nt], c, 0, 0, 0);
                    acc[mi][nt] = c;
                }
            pA0 = nA0; pA1 = nA1; pB0 = nB0; pB1 = nB1;
        }
    }

    // ---- epilogue: C[m = m0+mi*16+fq*4+r][n = wn+nt*16+fr] ----
    const float leak = leak_ptr[0], il = 1.0f - leak;
    #pragma unroll
    for (int mi = 0; mi < 2; ++mi)
        #pragma unroll
        for (int r = 0; r < 4; ++r) {
            int m = m0 + mi * 16 + fq * 4 + r;
            #pragma unroll
            for (int nt = 0; nt < 4; ++nt) {
                int n = wn + nt * 16 + fr;
                size_t idx = (size_t)m * H_DIM + n;
                float old = s_prev[idx];
                float pre = acc[mi][nt][r];
                float e = __expf(2.0f * pre);
                float th = 1.0f - 2.0f / (e + 1.0f);
                s_new[idx] = leak * th + il * old;
            }
        }
}

__global__ __launch_bounds__(256) void upd_kernel(
        const float* __restrict__ A1a, int K1a, const float* __restrict__ spa,
        const unsigned short* __restrict__ B1ha, const unsigned short* __restrict__ B1la,
        const unsigned short* __restrict__ B2ha, const unsigned short* __restrict__ B2la,
        const float* __restrict__ AGGa, float* __restrict__ sna,
        const float* __restrict__ A1b, int K1b, const float* __restrict__ spb,
        const unsigned short* __restrict__ B1hb, const unsigned short* __restrict__ B1lb,
        const unsigned short* __restrict__ B2hb, const unsigned short* __restrict__ B2lb,
        const float* __restrict__ AGGb, float* __restrict__ snb,
        const float* __restrict__ leak_ptr, int merged) {
    if (merged) {
        const int task = blockIdx.x & 1;
        const int m0 = (blockIdx.x >> 1) * 32;
        if (task == 0)
            upd_body(A1a, K1a, spa, B1ha, B1la, B2ha, B2la, AGGa, sna, leak_ptr, m0);
        else
            upd_body(A1b, K1b, spb, B1hb, B1lb, B2hb, B2lb, AGGb, snb, leak_ptr, m0);
    } else {
        upd_body(A1a, K1a, spa, B1ha, B1la, B2ha, B2la, AGGa, sna, leak_ptr, blockIdx.x * 32);
    }
}

// ---------------- launch ----------------

extern "C" void kernel_launch(void* const* d_in, const int* in_sizes, int n_in,
                              void* d_out, int out_size, void* d_ws, size_t ws_size,
                              hipStream_t stream) {
    const float* x        = (const float*)d_in[0];
    const int*   edge     = (const int*)d_in[1];
    const float* w_in0    = (const float*)d_in[2];
    const float* w_rec0   = (const float*)d_in[3];
    const float* w_in1    = (const float*)d_in[4];
    const float* w_rec1   = (const float*)d_in[5];
    const float* leak_ptr = (const float*)d_in[6];

    const int* src = edge;
    const int* dst = edge + E_EDGES;

    char* ws = (char*)d_ws;
    size_t off = 0;
    auto alloc = [&](size_t bytes) -> char* {
        char* p = ws + off;
        off += (bytes + 255) & ~(size_t)255;
        return p;
    };
    const size_t state_bytes = (size_t)N_NODES * H_DIM * sizeof(float);
    // ping-pong buffers; s1 buffer 0 is d_out (s1(7) lands in s1b[(7+1)&1] = s1b[0])
    float* s0b[2]; float* s1b[2];
    s0b[0] = (float*)alloc(state_bytes);
    s0b[1] = (float*)alloc(state_bytes);
    s1b[0] = (float*)d_out;
    s1b[1] = (float*)alloc(state_bytes);
    float* AGG0 = (float*)alloc(state_bytes);
    float* AGG1 = (float*)alloc(state_bytes);
    unsigned short* w0h  = (unsigned short*)alloc(256 * 128 * 2);
    unsigned short* w0l  = (unsigned short*)alloc(256 * 128 * 2);
    unsigned short* wr0h = (unsigned short*)alloc(256 * 256 * 2);
    unsigned short* wr0l = (unsigned short*)alloc(256 * 256 * 2);
    unsigned short* w1h  = (unsigned short*)alloc(256 * 256 * 2);
    unsigned short* w1l  = (unsigned short*)alloc(256 * 256 * 2);
    unsigned short* wr1h = (unsigned short*)alloc(256 * 256 * 2);
    unsigned short* wr1l = (unsigned short*)alloc(256 * 256 * 2);
    int* row_ptr = (int*)alloc((N_NODES + 1) * sizeof(int));
    int* cursors = (int*)alloc(N_NODES * sizeof(int));
    int* counts  = (int*)alloc(N_NODES * sizeof(int));
    unsigned short* col = (unsigned short*)alloc((size_t)E_EDGES * sizeof(unsigned short));

    hipMemsetAsync(s0b[0], 0, state_bytes, stream);
    hipMemsetAsync(s1b[0], 0, state_bytes, stream);
    hipMemsetAsync(counts, 0, N_NODES * sizeof(int), stream);

    cvt_frag<<<16, 256, 0, stream>>>(w_in0, F_IN, w0h, w0l);
    cvt_frag<<<32, 256, 0, stream>>>(w_rec0, H_DIM, wr0h, wr0l);
    cvt_frag<<<32, 256, 0, stream>>>(w_in1, H_DIM, w1h, w1l);
    cvt_frag<<<32, 256, 0, stream>>>(w_rec1, H_DIM, wr1h, wr1l);

    count_kernel<<<(E_EDGES + 255) / 256, 256, 0, stream>>>(dst, counts, E_EDGES);
    scan_kernel<<<1, 1024, 0, stream>>>(counts, row_ptr, cursors, N_NODES);
    fill_kernel<<<(E_EDGES + 255) / 256, 256, 0, stream>>>(src, dst, cursors, col, E_EDGES);

    dim3 g_upd1(G_UPD);      // 625
    dim3 g_upd2(2 * G_UPD);  // 1250 merged
    dim3 g_agg1(G_AGG);      // 5000
    dim3 g_agg2(2 * G_AGG);  // 10000 dual-buffer

    // Serial dependency-exact schedule (s0(t) in s0b[(t+1)&1], s1(t) in s1b[(t+1)&1]):
    //   UPD0(0)                       dense only
    //   AGG(s0(0) -> AGG0)
    //   t = 0..6:
    //     UPDm(t) = UPD1(t) + UPD0(t+1)     (independent pair, merged)
    //     AGG dual: s1(t) -> AGG1 ; s0(t+1) -> AGG0    (single at t=6)
    //   UPD1(7)                       writes d_out

    // UPD0(0): A=x(0), no AGG
    upd_kernel<<<g_upd1, 256, 0, stream>>>(
        x, F_IN, s0b[0], w0h, w0l, nullptr, nullptr, nullptr, s0b[1],
        nullptr, 0, nullptr, nullptr, nullptr, nullptr, nullptr, nullptr, nullptr,
        leak_ptr, 0);
    // AGG0(1): gather s0(0)
    agg_kernel<<<g_agg1, 256, 0, stream>>>(s0b[1], AGG0, nullptr, nullptr, row_ptr, col);

    for (int t = 0; t < 7; ++t) {
        const float* s0_t  = s0b[(t + 1) & 1];   // s0(t)
        float* s0_n        = s0b[t & 1];         // s0(t+1) dest
        const float* s1_p  = s1b[t & 1];         // s1(t-1)
        float* s1_t        = s1b[(t + 1) & 1];   // s1(t) dest
        const float* xt1 = x + (size_t)(t + 1) * N_NODES * F_IN;
        int dg1 = (t > 0) ? 1 : 0;               // s1(-1) = 0 -> skip AGG term

        // UPDm(t): task a = UPD1(t), task b = UPD0(t+1)
        upd_kernel<<<g_upd2, 256, 0, stream>>>(
            s0_t, H_DIM, s1_p, w1h, w1l,
            dg1 ? wr1h : nullptr, dg1 ? wr1l : nullptr, AGG1, s1_t,
            xt1, F_IN, s0_t, w0h, w0l, wr0h, wr0l, AGG0, s0_n,
            leak_ptr, 1);

        if (t < 6) {
            // dual gather: s1(t) -> AGG1 and s0(t+1) -> AGG0
            agg_kernel<<<g_agg2, 256, 0, stream>>>(s1_t, AGG1, s0_n, AGG0, row_ptr, col);
        } else {
            // only AGG1(7): gather s1(6)
            agg_kernel<<<g_agg1, 256, 0, stream>>>(s1_t, AGG1, nullptr, nullptr, row_ptr, col);
        }
    }

    // UPD1(7): A = s0(7) = s0b[0], sp = s1(6) = s1b[1], writes s1b[0] = d_out
    upd_kernel<<<g_upd1, 256, 0, stream>>>(
        s0b[0], H_DIM, s1b[1], w1h, w1l, wr1h, wr1l, AGG1, s1b[0],
        nullptr, 0, nullptr, nullptr, nullptr, nullptr, nullptr, nullptr, nullptr,
        leak_ptr, 0);
}